// Round 6
// baseline (232.857 us; speedup 1.0000x reference)
//
#include <hip/hip_runtime.h>

// GRU fused, MI355X/gfx950 — round 8.
// r7 post-mortem: no spills, occupancy proven ~neutral (r2 2blk 96us ==
// r7 1blk 100us): per-block-step cost pinned ~4200cyc, VALU/trans-issue
// bound (VALUBusy*t = ~2000cyc/SIMD/step) + barrier-locked LDS bursts.
// r8 cuts issue work + LDS traffic, identical math:
//  * 4 waves x 32 cols (ut=2), MB=16, launch_bounds(256,1): 512-reg cap
//    (no r6 spill), h LDS re-read halved (4 waves not 8), smaller barrier.
//  * sigmoid/tanh scale consts FOLDED into bf16 weights (-1.4427 / 2.8854):
//    -3 mul/eval.
//  * bias via k=28 slot of x-weight frag (B-frag carries 1.0 there):
//    az/ag/ax init = 0, -24 bias VGPRs.
//  * x from GLOBAL per step (L2-resident; clamped 2nd float4, garbage
//    hits zero weights) + v_cvt_pk_bf16_f32 to build frags; h pack also
//    cvt_pk. LDS 74KB -> 14.5KB, init (and its conflicts) ~gone.

#define B_  16384
#define T_  28
#define F_  28
#define H_  128
#define C_  10
#define MB  16     // batch rows per block
#define LHS 136    // lh row stride in ushorts (272 B; balanced banks for b128/b64)

typedef short  short8  __attribute__((ext_vector_type(8)));
typedef float  f32x4   __attribute__((ext_vector_type(4)));
typedef unsigned uint4v __attribute__((ext_vector_type(4)));

__device__ __forceinline__ unsigned short f2bf(float f) {   // RNE fp32->bf16
    unsigned u = __builtin_bit_cast(unsigned, f);
    u += 0x7fffu + ((u >> 16) & 1u);
    return (unsigned short)(u >> 16);
}
__device__ __forceinline__ float bf2f(unsigned short h) {
    unsigned u = ((unsigned)h) << 16;
    return __builtin_bit_cast(float, u);
}
__device__ __forceinline__ unsigned cvt_pk_bf16(float lo, float hi) {
    unsigned r;
    asm("v_cvt_pk_bf16_f32 %0, %1, %2" : "=v"(r) : "v"(lo), "v"(hi));
    return r;
}

#define MS (-1.442695040888963f)   // z,r pre-scale (sig(x)=rcp(1+exp2(-x/ln2)))
#define TS ( 2.885390081777927f)   // tanh pre-scale (tanh=1-2*rcp(1+exp2(2x/ln2)))

__global__ __launch_bounds__(256, 1)
void gru_fused(const float* __restrict__ x,     // (B,T,F)
               const float* __restrict__ wk,    // (F,3H) = (28,384)
               const float* __restrict__ wrk,   // (H,3H) = (128,384)
               const float* __restrict__ bias,  // (2,3H)
               const float* __restrict__ dw,    // (H,C)
               const float* __restrict__ db,    // (C,)
               float* __restrict__ out)         // (B,C)
{
    // ---- LDS (~14.5 KB) ----
    __shared__ __align__(16) unsigned short lh[2][MB*LHS];      // 8704 B, double-buffered
    __shared__ float ldw[H_*C_];                                // 5120 B
    __shared__ float llog[MB][C_];                              // 640 B

    const int tid  = threadIdx.x;
    const int base = blockIdx.x * MB;
    const int lane = tid & 63;
    const int wc   = tid >> 6;    // wave id 0..3 -> 32-column slice (2 x 16)
    const int n    = lane & 15;   // B-operand outer (batch) / D col
    const int q    = lane >> 4;   // MFMA quad

    // ---- loop-invariant weight fragments -> REGISTERS (120 VGPR/wave) ----
    // A-frag (weights): elem(lane,j) = W'[k = kb*32 + q*8 + j][col], col = wc*32+ut*16+n
    // W' = W * MS (z,r) or W * TS (h). x-kernel k==28 row carries the bias.
    short8 wz[2][4], wr[2][4], wh[2][4];   // W_rec per [ut][kb]: 96 VGPR
    short8 xz[2], xr[2], xh[2];            // kernel (K pad 28->32, k28=bias): 24 VGPR
    #pragma unroll
    for (int ut = 0; ut < 2; ++ut) {
        const int col = wc*32 + ut*16 + n;
        #pragma unroll
        for (int kb = 0; kb < 4; ++kb) {
            const int k0 = kb*32 + q*8;
            short8 vz, vr, vh;
            #pragma unroll
            for (int j = 0; j < 8; ++j) {
                const float* wp = wrk + (size_t)(k0 + j)*384 + col;
                vz[j] = (short)f2bf(wp[0]   * MS);
                vr[j] = (short)f2bf(wp[128] * MS);
                vh[j] = (short)f2bf(wp[256] * TS);
            }
            wz[ut][kb] = vz; wr[ut][kb] = vr; wh[ut][kb] = vh;
        }
        short8 vz, vr, vh;
        #pragma unroll
        for (int j = 0; j < 8; ++j) {
            const int k = q*8 + j;
            if (k < F_) {
                const float* wp = wk + (size_t)k*384 + col;
                vz[j] = (short)f2bf(wp[0]   * MS);
                vr[j] = (short)f2bf(wp[128] * MS);
                vh[j] = (short)f2bf(wp[256] * TS);
            } else if (k == F_) {   // bias row (B-frag has 1.0 here)
                vz[j] = (short)f2bf((bias[col]       + bias[384 + col]) * MS);
                vr[j] = (short)f2bf((bias[128 + col] + bias[512 + col]) * MS);
                vh[j] = (short)f2bf( bias[256 + col]                    * TS);
            } else { vz[j] = 0; vr[j] = 0; vh[j] = 0; }
        }
        xz[ut] = vz; xr[ut] = vr; xh[ut] = vh;
    }

    // br_h must stay separate (rec-h acc has no spare k slot): 8 VGPR, pre-scaled
    f32x4 bh4[2];
    #pragma unroll
    for (int ut = 0; ut < 2; ++ut)
        #pragma unroll
        for (int reg = 0; reg < 4; ++reg)
            bh4[ut][reg] = bias[640 + wc*32 + ut*16 + q*4 + reg] * TS;

    // ---- dense weights / h0 ----
    for (int i = tid; i < H_*C_; i += 256) ldw[i] = dw[i];
    for (int i = tid; i < MB*LHS/2; i += 256) ((unsigned*)lh[0])[i] = 0u;

    __syncthreads();   // init visible

    float hm[2][4];               // fp32 h master: unit wc*32+ut*16+q*4+reg, batch n
    #pragma unroll
    for (int ut = 0; ut < 2; ++ut)
        #pragma unroll
        for (int r = 0; r < 4; ++r) hm[ut][r] = 0.f;

    const float* xrow = x + (size_t)(base + n)*(T_*F_);
    const int xo1 = q*8;
    const int xo2 = (q < 3) ? q*8 + 4 : 24;   // clamped: in-bounds garbage x zero-weight
    const bool q3 = (q == 3);
    const int rbase = n*LHS;
    const int wbase = n*LHS + wc*32 + q*4;    // h write base (ut adds 16)

    #pragma unroll 1
    for (int t = 0; t < T_; ++t) {
        const unsigned short* __restrict__ lhr = lh[t & 1];
        unsigned short* __restrict__ lhw = lh[(t + 1) & 1];

        // x for this step from global (consumed late, latency hides under MFMAs)
        float4 a0 = *(const float4*)(xrow + t*F_ + xo1);
        float4 a1 = *(const float4*)(xrow + t*F_ + xo2);

        // h B-frags (shared by both ut slices): 4x b128, conflict-free
        short8 hb[4];
        #pragma unroll
        for (int kb = 0; kb < 4; ++kb)
            hb[kb] = *(const short8*)&lhr[rbase + kb*32 + q*8];

        // x B-frag: 4x cvt_pk; k==28 slot forced to 1.0 (bias multiplier)
        uint4v xv;
        xv[0] = cvt_pk_bf16(a0.x, a0.y);
        xv[1] = cvt_pk_bf16(a0.z, a0.w);
        xv[2] = q3 ? 0x3f80u : cvt_pk_bf16(a1.x, a1.y);
        xv[3] = cvt_pk_bf16(a1.z, a1.w);
        const short8 xbv = __builtin_bit_cast(short8, xv);

        f32x4 az[2], ag[2], ax[2], ah[2];
        #pragma unroll
        for (int ut = 0; ut < 2; ++ut) {
            az[ut] = (f32x4){0.f,0.f,0.f,0.f};
            ag[ut] = (f32x4){0.f,0.f,0.f,0.f};
            ax[ut] = (f32x4){0.f,0.f,0.f,0.f};
            ah[ut] = bh4[ut];
            #pragma unroll
            for (int kb = 0; kb < 4; ++kb) {
                az[ut] = __builtin_amdgcn_mfma_f32_16x16x32_bf16(wz[ut][kb], hb[kb], az[ut], 0,0,0);
                ag[ut] = __builtin_amdgcn_mfma_f32_16x16x32_bf16(wr[ut][kb], hb[kb], ag[ut], 0,0,0);
                ah[ut] = __builtin_amdgcn_mfma_f32_16x16x32_bf16(wh[ut][kb], hb[kb], ah[ut], 0,0,0);
            }
            az[ut] = __builtin_amdgcn_mfma_f32_16x16x32_bf16(xz[ut], xbv, az[ut], 0,0,0);
            ag[ut] = __builtin_amdgcn_mfma_f32_16x16x32_bf16(xr[ut], xbv, ag[ut], 0,0,0);
            ax[ut] = __builtin_amdgcn_mfma_f32_16x16x32_bf16(xh[ut], xbv, ax[ut], 0,0,0);
        }

        // gates (pre-scaled accs): z=rcp(1+exp2(az)), hh=1-2*rcp(1+exp2(ax+r*ah))
        #pragma unroll
        for (int ut = 0; ut < 2; ++ut) {
            float hn[4];
            #pragma unroll
            for (int reg = 0; reg < 4; ++reg) {
                float z  = __builtin_amdgcn_rcpf(1.0f + __builtin_amdgcn_exp2f(az[ut][reg]));
                float r  = __builtin_amdgcn_rcpf(1.0f + __builtin_amdgcn_exp2f(ag[ut][reg]));
                float ta = ax[ut][reg] + r * ah[ut][reg];
                float hh = 1.0f - 2.0f * __builtin_amdgcn_rcpf(1.0f + __builtin_amdgcn_exp2f(ta));
                float hv = hh + z * (hm[ut][reg] - hh);
                hm[ut][reg] = hv; hn[reg] = hv;
            }
            uint2 pk;
            pk.x = cvt_pk_bf16(hn[0], hn[1]);
            pk.y = cvt_pk_bf16(hn[2], hn[3]);
            *(uint2*)&lhw[wbase + ut*16] = pk;
        }

        __syncthreads();   // h_{t+1} published
    }

    // ---- dense + softmax epilogue (final h in lh[0]: last write t=27 -> (27+1)&1) ----
    if (tid < MB*C_) {
        const int row = tid / C_, c = tid - row*C_;
        float s = db[c];
        #pragma unroll
        for (int u0 = 0; u0 < H_; u0 += 8) {
            short8 hv = *(const short8*)&lh[0][row*LHS + u0];
            #pragma unroll
            for (int j = 0; j < 8; ++j)
                s += bf2f((unsigned short)hv[j]) * ldw[(u0+j)*C_ + c];
        }
        llog[row][c] = s;
    }
    __syncthreads();
    if (tid < MB) {
        const int row = tid;
        float m = llog[row][0];
        #pragma unroll
        for (int c = 1; c < C_; ++c) m = fmaxf(m, llog[row][c]);
        float e[C_], s = 0.f;
        #pragma unroll
        for (int c = 0; c < C_; ++c) {
            e[c] = __builtin_amdgcn_exp2f((llog[row][c] - m) * 1.442695040888963f);
            s += e[c];
        }
        const float inv = __builtin_amdgcn_rcpf(s);
        float* o = out + (size_t)(base + row)*C_;
        #pragma unroll
        for (int c = 0; c < C_; ++c) o[c] = e[c] * inv;
    }
}

extern "C" void kernel_launch(void* const* d_in, const int* in_sizes, int n_in,
                              void* d_out, int out_size, void* d_ws, size_t ws_size,
                              hipStream_t stream) {
    const float* x   = (const float*)d_in[0];
    const float* wk  = (const float*)d_in[1];
    const float* wrk = (const float*)d_in[2];
    const float* bs  = (const float*)d_in[3];
    const float* dw  = (const float*)d_in[4];
    const float* db  = (const float*)d_in[5];
    (void)in_sizes; (void)n_in; (void)out_size; (void)d_ws; (void)ws_size;
    gru_fused<<<dim3(B_/MB), dim3(256), 0, stream>>>(x, wk, wrk, bs, dw, db, (float*)d_out);
}

// Round 9
// 191.083 us; speedup vs baseline: 1.2186x; 1.2186x over previous
//
#include <hip/hip_runtime.h>

// GRU fused, MI355X/gfx950 — round 9 (2nd resubmit; two consecutive infra
// failures "container failed twice" — no kernel signal either time).
// r8 post-mortem: per-step SYNCHRONOUS global x-load + 1 resident block
// killed it (180us). r9 = r8's lean math (folded scales, k28-bias,
// cvt_pk) + r2's proven x REGISTER-PREFETCH (one full step of latency
// cover) + small-LDS many-block residency:
//   8 waves x 16 cols, MB=16, grid 1024, LB(512,4): live ~122 regs -> no
//   spill at the 128 cap; LDS 14.5KB -> 4 blocks/CU; desynced barriers.

#define B_  16384
#define T_  28
#define F_  28
#define H_  128
#define C_  10
#define MB  16     // batch rows per block
#define LHS 136    // lh row stride in ushorts (272 B; balanced banks for b128/b64)

typedef short  short8  __attribute__((ext_vector_type(8)));
typedef float  f32x4   __attribute__((ext_vector_type(4)));
typedef unsigned uint4v __attribute__((ext_vector_type(4)));

__device__ __forceinline__ unsigned short f2bf(float f) {   // RNE fp32->bf16
    unsigned u = __builtin_bit_cast(unsigned, f);
    u += 0x7fffu + ((u >> 16) & 1u);
    return (unsigned short)(u >> 16);
}
__device__ __forceinline__ float bf2f(unsigned short h) {
    unsigned u = ((unsigned)h) << 16;
    return __builtin_bit_cast(float, u);
}
__device__ __forceinline__ unsigned cvt_pk_bf16(float lo, float hi) {
    unsigned r;
    asm("v_cvt_pk_bf16_f32 %0, %1, %2" : "=v"(r) : "v"(lo), "v"(hi));
    return r;
}

#define MS (-1.442695040888963f)   // z,r pre-scale (sig(x)=rcp(1+exp2(-x/ln2)))
#define TS ( 2.885390081777927f)   // tanh pre-scale (tanh=1-2*rcp(1+exp2(2x/ln2)))

__global__ __launch_bounds__(512, 4)
void gru_fused(const float* __restrict__ x,     // (B,T,F)
               const float* __restrict__ wk,    // (F,3H) = (28,384)
               const float* __restrict__ wrk,   // (H,3H) = (128,384)
               const float* __restrict__ bias,  // (2,3H)
               const float* __restrict__ dw,    // (H,C)
               const float* __restrict__ db,    // (C,)
               float* __restrict__ out)         // (B,C)
{
    // ---- LDS (~14.5 KB) -> 4 blocks/CU ----
    __shared__ __align__(16) unsigned short lh[2][MB*LHS];      // 8704 B, double-buffered
    __shared__ float ldw[H_*C_];                                // 5120 B
    __shared__ float llog[MB][C_];                              // 640 B

    const int tid  = threadIdx.x;
    const int base = blockIdx.x * MB;
    const int lane = tid & 63;
    const int wc   = tid >> 6;    // wave id 0..7 -> 16-column slice
    const int n    = lane & 15;   // B-operand outer (batch) / D col
    const int q    = lane >> 4;   // MFMA quad
    const int col  = wc*16 + n;   // weight column (A operand)

    // ---- loop-invariant weight fragments -> REGISTERS (60 VGPR/wave) ----
    // A-frag: elem(lane,j) = W'[k = kb*32 + q*8 + j][col]
    // W' = W * MS (z,r) or W * TS (h). x-kernel k==28 row carries the bias.
    short8 wzr[4], wrr[4], whr[4];   // W_rec per kb: 48 VGPR
    short8 xzr, xrr, xhr;            // kernel (K pad 28->32, k28=bias): 12 VGPR
    {
        #pragma unroll
        for (int kb = 0; kb < 4; ++kb) {
            const int k0 = kb*32 + q*8;
            short8 vz, vr, vh;
            #pragma unroll
            for (int j = 0; j < 8; ++j) {
                const float* wp = wrk + (size_t)(k0 + j)*384 + col;
                vz[j] = (short)f2bf(wp[0]   * MS);
                vr[j] = (short)f2bf(wp[128] * MS);
                vh[j] = (short)f2bf(wp[256] * TS);
            }
            wzr[kb] = vz; wrr[kb] = vr; whr[kb] = vh;
        }
        short8 vz, vr, vh;
        #pragma unroll
        for (int j = 0; j < 8; ++j) {
            const int k = q*8 + j;
            if (k < F_) {
                const float* wp = wk + (size_t)k*384 + col;
                vz[j] = (short)f2bf(wp[0]   * MS);
                vr[j] = (short)f2bf(wp[128] * MS);
                vh[j] = (short)f2bf(wp[256] * TS);
            } else if (k == F_) {   // bias row (B-frag has 1.0 here)
                vz[j] = (short)f2bf((bias[col]       + bias[384 + col]) * MS);
                vr[j] = (short)f2bf((bias[128 + col] + bias[512 + col]) * MS);
                vh[j] = (short)f2bf( bias[256 + col]                    * TS);
            } else { vz[j] = 0; vr[j] = 0; vh[j] = 0; }
        }
        xzr = vz; xrr = vr; xhr = vh;
    }

    // br_h (rec-h acc init), pre-scaled: 4 VGPR
    f32x4 bh4;
    #pragma unroll
    for (int reg = 0; reg < 4; ++reg)
        bh4[reg] = bias[640 + wc*16 + q*4 + reg] * TS;

    // ---- dense weights / h0 ----
    for (int i = tid; i < H_*C_; i += 512) ldw[i] = dw[i];
    for (int i = tid; i < MB*LHS/2; i += 512) ((unsigned*)lh[0])[i] = 0u;

    __syncthreads();   // init visible

    float hm[4];                  // fp32 h master: unit wc*16+q*4+reg, batch n
    hm[0]=0.f; hm[1]=0.f; hm[2]=0.f; hm[3]=0.f;

    const float* xrow = x + (size_t)(base + n)*(T_*F_);
    const int xo1 = q*8;
    const int xo2 = (q < 3) ? q*8 + 4 : 24;   // clamped: in-bounds garbage x zero-weight
    const bool q3 = (q == 3);
    const int rbase = n*LHS;
    const int wbase = n*LHS + wc*16 + q*4;    // h write base

    // prefetch x for t=0
    float4 a0 = *(const float4*)(xrow + xo1);
    float4 a1 = *(const float4*)(xrow + xo2);

    #pragma unroll 1
    for (int t = 0; t < T_; ++t) {
        const unsigned short* __restrict__ lhr = lh[t & 1];
        unsigned short* __restrict__ lhw = lh[(t + 1) & 1];

        // x B-frag from the prefetched regs (4x cvt_pk; k==28 slot = 1.0 bias mult)
        uint4v xv;
        xv[0] = cvt_pk_bf16(a0.x, a0.y);
        xv[1] = cvt_pk_bf16(a0.z, a0.w);
        xv[2] = q3 ? 0x3f80u : cvt_pk_bf16(a1.x, a1.y);
        xv[3] = cvt_pk_bf16(a1.z, a1.w);
        const short8 xbv = __builtin_bit_cast(short8, xv);

        // issue NEXT step's x loads now: a full step (~4000cy) of latency cover
        if (t + 1 < T_) {
            a0 = *(const float4*)(xrow + (t+1)*F_ + xo1);
            a1 = *(const float4*)(xrow + (t+1)*F_ + xo2);
        }

        // h B-frags: 4x b128, conflict-free
        short8 hb[4];
        #pragma unroll
        for (int kb = 0; kb < 4; ++kb)
            hb[kb] = *(const short8*)&lhr[rbase + kb*32 + q*8];

        f32x4 az = (f32x4){0.f,0.f,0.f,0.f};
        f32x4 ag = (f32x4){0.f,0.f,0.f,0.f};
        f32x4 ax = (f32x4){0.f,0.f,0.f,0.f};
        f32x4 ah = bh4;
        #pragma unroll
        for (int kb = 0; kb < 4; ++kb) {
            az = __builtin_amdgcn_mfma_f32_16x16x32_bf16(wzr[kb], hb[kb], az, 0,0,0);
            ag = __builtin_amdgcn_mfma_f32_16x16x32_bf16(wrr[kb], hb[kb], ag, 0,0,0);
            ah = __builtin_amdgcn_mfma_f32_16x16x32_bf16(whr[kb], hb[kb], ah, 0,0,0);
        }
        az = __builtin_amdgcn_mfma_f32_16x16x32_bf16(xzr, xbv, az, 0,0,0);
        ag = __builtin_amdgcn_mfma_f32_16x16x32_bf16(xrr, xbv, ag, 0,0,0);
        ax = __builtin_amdgcn_mfma_f32_16x16x32_bf16(xhr, xbv, ax, 0,0,0);

        // gates (pre-scaled accs): z=rcp(1+exp2(az)), hh=1-2*rcp(1+exp2(ax+r*ah))
        float hn[4];
        #pragma unroll
        for (int reg = 0; reg < 4; ++reg) {
            float z  = __builtin_amdgcn_rcpf(1.0f + __builtin_amdgcn_exp2f(az[reg]));
            float r  = __builtin_amdgcn_rcpf(1.0f + __builtin_amdgcn_exp2f(ag[reg]));
            float ta = ax[reg] + r * ah[reg];
            float hh = 1.0f - 2.0f * __builtin_amdgcn_rcpf(1.0f + __builtin_amdgcn_exp2f(ta));
            float hv = hh + z * (hm[reg] - hh);
            hm[reg] = hv; hn[reg] = hv;
        }
        uint2 pk;
        pk.x = cvt_pk_bf16(hn[0], hn[1]);
        pk.y = cvt_pk_bf16(hn[2], hn[3]);
        *(uint2*)&lhw[wbase] = pk;

        __syncthreads();   // h_{t+1} published
    }

    // ---- dense + softmax epilogue (final h in lh[0]: last write t=27 -> (27+1)&1) ----
    if (tid < MB*C_) {
        const int row = tid / C_, c = tid - row*C_;
        float s = db[c];
        #pragma unroll
        for (int u0 = 0; u0 < H_; u0 += 8) {
            short8 hv = *(const short8*)&lh[0][row*LHS + u0];
            #pragma unroll
            for (int j = 0; j < 8; ++j)
                s += bf2f((unsigned short)hv[j]) * ldw[(u0+j)*C_ + c];
        }
        llog[row][c] = s;
    }
    __syncthreads();
    if (tid < MB) {
        const int row = tid;
        float m = llog[row][0];
        #pragma unroll
        for (int c = 1; c < C_; ++c) m = fmaxf(m, llog[row][c]);
        float e[C_], s = 0.f;
        #pragma unroll
        for (int c = 0; c < C_; ++c) {
            e[c] = __builtin_amdgcn_exp2f((llog[row][c] - m) * 1.442695040888963f);
            s += e[c];
        }
        const float inv = __builtin_amdgcn_rcpf(s);
        float* o = out + (size_t)(base + row)*C_;
        #pragma unroll
        for (int c = 0; c < C_; ++c) o[c] = e[c] * inv;
    }
}

extern "C" void kernel_launch(void* const* d_in, const int* in_sizes, int n_in,
                              void* d_out, int out_size, void* d_ws, size_t ws_size,
                              hipStream_t stream) {
    const float* x   = (const float*)d_in[0];
    const float* wk  = (const float*)d_in[1];
    const float* wrk = (const float*)d_in[2];
    const float* bs  = (const float*)d_in[3];
    const float* dw  = (const float*)d_in[4];
    const float* db  = (const float*)d_in[5];
    (void)in_sizes; (void)n_in; (void)out_size; (void)d_ws; (void)ws_size;
    gru_fused<<<dim3(B_/MB), dim3(512), 0, stream>>>(x, wk, wrk, bs, dw, db, (float*)d_out);
}

// Round 10
// 155.538 us; speedup vs baseline: 1.4971x; 1.2285x over previous
//
#include <hip/hip_runtime.h>

// GRU fused, MI355X/gfx950 — round 10.
// Cross-round model: per-block-step cost Sb ~1.4-1.9us is nearly FIXED
// (latency: barrier + LDS roundtrip + dependent MFMA/trans chains), not
// throughput: r3 MB16 Sb~1.4, r7 MB32 Sb~1.8 (2x work = +30%), occupancy
// proven ~irrelevant (r2/r3/r7/r9), 128-reg cap ALWAYS spills (r3/r5/r6/r9;
// unified VGPR+AGPR file). Therefore: AMORTIZE the fixed step cost.
//   MB=64 (4 batch tiles/wave), grid 256 = exactly 1 block/CU, 8 waves x
//   16 cols, LB(512,2) = 256-reg budget (only spill-free config: r7).
//   Per step: 4 independent MFMA chains/wave (intra-wave ILP, r2 lesson).
// Keeps: folded sig/tanh scales, k28-bias row, cvt_pk packing, x register
// prefetch one step ahead, 1 barrier/step.

#define B_  16384
#define T_  28
#define F_  28
#define H_  128
#define C_  10
#define MB  64     // batch rows per block (4 tiles of 16)
#define MT  4      // batch tiles per wave
#define LHS 136    // lh row stride in ushorts (272 B; balanced banks for b128/b64)

typedef short  short8  __attribute__((ext_vector_type(8)));
typedef float  f32x4   __attribute__((ext_vector_type(4)));
typedef unsigned uint4v __attribute__((ext_vector_type(4)));

__device__ __forceinline__ unsigned short f2bf(float f) {   // RNE fp32->bf16
    unsigned u = __builtin_bit_cast(unsigned, f);
    u += 0x7fffu + ((u >> 16) & 1u);
    return (unsigned short)(u >> 16);
}
__device__ __forceinline__ float bf2f(unsigned short h) {
    unsigned u = ((unsigned)h) << 16;
    return __builtin_bit_cast(float, u);
}
__device__ __forceinline__ unsigned cvt_pk_bf16(float lo, float hi) {
    unsigned r;
    asm("v_cvt_pk_bf16_f32 %0, %1, %2" : "=v"(r) : "v"(lo), "v"(hi));
    return r;
}

#define MS (-1.442695040888963f)   // z,r pre-scale (sig(x)=rcp(1+exp2(-x/ln2)))
#define TS ( 2.885390081777927f)   // tanh pre-scale (tanh=1-2*rcp(1+exp2(2x/ln2)))

__global__ __launch_bounds__(512, 2)
void gru_fused(const float* __restrict__ x,     // (B,T,F)
               const float* __restrict__ wk,    // (F,3H) = (28,384)
               const float* __restrict__ wrk,   // (H,3H) = (128,384)
               const float* __restrict__ bias,  // (2,3H)
               const float* __restrict__ dw,    // (H,C)
               const float* __restrict__ db,    // (C,)
               float* __restrict__ out)         // (B,C)
{
    // ---- LDS (~43 KB) ----
    __shared__ __align__(16) unsigned short lh[2][MB*LHS];      // 34816 B, double-buffered
    __shared__ float ldw[H_*C_];                                // 5120 B
    __shared__ float llog[MB][C_];                              // 2560 B

    const int tid  = threadIdx.x;
    const int base = blockIdx.x * MB;
    const int lane = tid & 63;
    const int wc   = tid >> 6;    // wave id 0..7 -> 16-column slice
    const int n    = lane & 15;   // B-operand outer (batch within tile) / D col
    const int q    = lane >> 4;   // MFMA quad
    const int col  = wc*16 + n;   // weight column (A operand)

    // ---- loop-invariant weight fragments -> REGISTERS (60 VGPR/wave) ----
    // A-frag: elem(lane,j) = W'[k = kb*32 + q*8 + j][col]
    // W' = W * MS (z,r) or W * TS (h). x-kernel k==28 row carries the bias.
    short8 wzr[4], wrr[4], whr[4];   // W_rec per kb: 48 VGPR
    short8 xzr, xrr, xhr;            // kernel (K pad 28->32, k28=bias): 12 VGPR
    {
        #pragma unroll
        for (int kb = 0; kb < 4; ++kb) {
            const int k0 = kb*32 + q*8;
            short8 vz, vr, vh;
            #pragma unroll
            for (int j = 0; j < 8; ++j) {
                const float* wp = wrk + (size_t)(k0 + j)*384 + col;
                vz[j] = (short)f2bf(wp[0]   * MS);
                vr[j] = (short)f2bf(wp[128] * MS);
                vh[j] = (short)f2bf(wp[256] * TS);
            }
            wzr[kb] = vz; wrr[kb] = vr; whr[kb] = vh;
        }
        short8 vz, vr, vh;
        #pragma unroll
        for (int j = 0; j < 8; ++j) {
            const int k = q*8 + j;
            if (k < F_) {
                const float* wp = wk + (size_t)k*384 + col;
                vz[j] = (short)f2bf(wp[0]   * MS);
                vr[j] = (short)f2bf(wp[128] * MS);
                vh[j] = (short)f2bf(wp[256] * TS);
            } else if (k == F_) {   // bias row (B-frag has 1.0 here)
                vz[j] = (short)f2bf((bias[col]       + bias[384 + col]) * MS);
                vr[j] = (short)f2bf((bias[128 + col] + bias[512 + col]) * MS);
                vh[j] = (short)f2bf( bias[256 + col]                    * TS);
            } else { vz[j] = 0; vr[j] = 0; vh[j] = 0; }
        }
        xzr = vz; xrr = vr; xhr = vh;
    }

    // br_h (rec-h acc init), pre-scaled: 4 VGPR
    f32x4 bh4;
    #pragma unroll
    for (int reg = 0; reg < 4; ++reg)
        bh4[reg] = bias[640 + wc*16 + q*4 + reg] * TS;

    // ---- dense weights / h0 ----
    for (int i = tid; i < H_*C_; i += 512) ldw[i] = dw[i];
    for (int i = tid; i < MB*LHS/2; i += 512) ((unsigned*)lh[0])[i] = 0u;

    __syncthreads();   // init visible

    float hm[MT][4];              // fp32 h master: unit wc*16+q*4+reg, batch mt*16+n
    #pragma unroll
    for (int mt = 0; mt < MT; ++mt)
        #pragma unroll
        for (int r = 0; r < 4; ++r) hm[mt][r] = 0.f;

    // per-mt x row pointers + x prefetch for t=0 (32 VGPR)
    const int xo1 = q*8;
    const int xo2 = (q < 3) ? q*8 + 4 : 24;   // clamped: in-bounds garbage x zero-weight
    const bool q3 = (q == 3);
    const float* xrw[MT];
    float4 xa0[MT], xa1[MT];
    #pragma unroll
    for (int mt = 0; mt < MT; ++mt) {
        xrw[mt] = x + (size_t)(base + mt*16 + n)*(T_*F_);
        xa0[mt] = *(const float4*)(xrw[mt] + xo1);
        xa1[mt] = *(const float4*)(xrw[mt] + xo2);
    }

    const int wbase = wc*16 + q*4;    // unit base this lane owns

    #pragma unroll 1
    for (int t = 0; t < T_; ++t) {
        const unsigned short* __restrict__ lhr = lh[t & 1];
        unsigned short* __restrict__ lhw = lh[(t + 1) & 1];
        const bool pn = (t + 1 < T_);

        #pragma unroll
        for (int mt = 0; mt < MT; ++mt) {
            // x B-frag from prefetched regs (4x cvt_pk; k==28 slot = 1.0 bias mult)
            uint4v xv;
            xv[0] = cvt_pk_bf16(xa0[mt].x, xa0[mt].y);
            xv[1] = cvt_pk_bf16(xa0[mt].z, xa0[mt].w);
            xv[2] = q3 ? 0x3f80u : cvt_pk_bf16(xa1[mt].x, xa1[mt].y);
            xv[3] = cvt_pk_bf16(xa1[mt].z, xa1[mt].w);
            const short8 xbv = __builtin_bit_cast(short8, xv);

            // issue next step's x loads for this mt (full step of latency cover)
            if (pn) {
                xa0[mt] = *(const float4*)(xrw[mt] + (t+1)*F_ + xo1);
                xa1[mt] = *(const float4*)(xrw[mt] + (t+1)*F_ + xo2);
            }

            // h B-frags for this tile: 4x b128, conflict-free
            const int rbase = (mt*16 + n)*LHS;
            short8 hb[4];
            #pragma unroll
            for (int kb = 0; kb < 4; ++kb)
                hb[kb] = *(const short8*)&lhr[rbase + kb*32 + q*8];

            f32x4 az = (f32x4){0.f,0.f,0.f,0.f};
            f32x4 ag = (f32x4){0.f,0.f,0.f,0.f};
            f32x4 ax = (f32x4){0.f,0.f,0.f,0.f};
            f32x4 ah = bh4;
            #pragma unroll
            for (int kb = 0; kb < 4; ++kb) {
                az = __builtin_amdgcn_mfma_f32_16x16x32_bf16(wzr[kb], hb[kb], az, 0,0,0);
                ag = __builtin_amdgcn_mfma_f32_16x16x32_bf16(wrr[kb], hb[kb], ag, 0,0,0);
                ah = __builtin_amdgcn_mfma_f32_16x16x32_bf16(whr[kb], hb[kb], ah, 0,0,0);
            }
            az = __builtin_amdgcn_mfma_f32_16x16x32_bf16(xzr, xbv, az, 0,0,0);
            ag = __builtin_amdgcn_mfma_f32_16x16x32_bf16(xrr, xbv, ag, 0,0,0);
            ax = __builtin_amdgcn_mfma_f32_16x16x32_bf16(xhr, xbv, ax, 0,0,0);

            // gates (pre-scaled accs): z=rcp(1+exp2(az)), hh=1-2*rcp(1+exp2(ax+r*ah))
            float hn[4];
            #pragma unroll
            for (int reg = 0; reg < 4; ++reg) {
                float z  = __builtin_amdgcn_rcpf(1.0f + __builtin_amdgcn_exp2f(az[reg]));
                float r  = __builtin_amdgcn_rcpf(1.0f + __builtin_amdgcn_exp2f(ag[reg]));
                float ta = ax[reg] + r * ah[reg];
                float hh = 1.0f - 2.0f * __builtin_amdgcn_rcpf(1.0f + __builtin_amdgcn_exp2f(ta));
                float hv = hh + z * (hm[mt][reg] - hh);
                hm[mt][reg] = hv; hn[reg] = hv;
            }
            uint2 pk;
            pk.x = cvt_pk_bf16(hn[0], hn[1]);
            pk.y = cvt_pk_bf16(hn[2], hn[3]);
            *(uint2*)&lhw[rbase + wbase] = pk;
        }

        __syncthreads();   // h_{t+1} published
    }

    // ---- dense + softmax epilogue (final h in lh[0]: last write t=27 -> (27+1)&1) ----
    for (int i = tid; i < MB*C_; i += 512) {
        const int row = i / C_, c = i - row*C_;
        float s = db[c];
        #pragma unroll
        for (int u0 = 0; u0 < H_; u0 += 8) {
            short8 hv = *(const short8*)&lh[0][row*LHS + u0];
            #pragma unroll
            for (int j = 0; j < 8; ++j)
                s += bf2f((unsigned short)hv[j]) * ldw[(u0+j)*C_ + c];
        }
        llog[row][c] = s;
    }
    __syncthreads();
    if (tid < MB) {
        const int row = tid;
        float m = llog[row][0];
        #pragma unroll
        for (int c = 1; c < C_; ++c) m = fmaxf(m, llog[row][c]);
        float e[C_], s = 0.f;
        #pragma unroll
        for (int c = 0; c < C_; ++c) {
            e[c] = __builtin_amdgcn_exp2f((llog[row][c] - m) * 1.442695040888963f);
            s += e[c];
        }
        const float inv = __builtin_amdgcn_rcpf(s);
        float* o = out + (size_t)(base + row)*C_;
        #pragma unroll
        for (int c = 0; c < C_; ++c) o[c] = e[c] * inv;
    }
}

extern "C" void kernel_launch(void* const* d_in, const int* in_sizes, int n_in,
                              void* d_out, int out_size, void* d_ws, size_t ws_size,
                              hipStream_t stream) {
    const float* x   = (const float*)d_in[0];
    const float* wk  = (const float*)d_in[1];
    const float* wrk = (const float*)d_in[2];
    const float* bs  = (const float*)d_in[3];
    const float* dw  = (const float*)d_in[4];
    const float* db  = (const float*)d_in[5];
    (void)in_sizes; (void)n_in; (void)out_size; (void)d_ws; (void)ws_size;
    gru_fused<<<dim3(B_/MB), dim3(512), 0, stream>>>(x, wk, wrk, bs, dw, db, (float*)d_out);
}